// Round 5
// baseline (307.698 us; speedup 1.0000x reference)
//
#include <hip/hip_runtime.h>

typedef _Float16 f16;
typedef _Float16 half8 __attribute__((ext_vector_type(8)));
typedef float f32x4 __attribute__((ext_vector_type(4)));
typedef float f32x16 __attribute__((ext_vector_type(16)));
typedef unsigned u32x4 __attribute__((ext_vector_type(4)));

#define LDW 72  // padded LDS leading dim (f16): 144B row stride

// ---------------- K1: BN stats (atomic) + spin + BN apply + QKV projections ----------------
// grid 256 (1 block/CU guaranteed co-resident -> spin is safe).
// Stats partials atomicAdd'ed into sums[128]; weight staging overlaps the wait.
__global__ __launch_bounds__(256) void k_qkv(
    const float* __restrict__ x,
    const float* __restrict__ w1, const float* __restrict__ w2, const float* __restrict__ w3,
    const float* __restrict__ b1, const float* __restrict__ b2, const float* __restrict__ b3,
    const float* __restrict__ gamma, const float* __restrict__ beta,
    float* __restrict__ sums, unsigned* __restrict__ ctr, unsigned* __restrict__ mergecnt,
    f16* __restrict__ Q, f16* __restrict__ Kx, f16* __restrict__ Vt){
    __shared__ f16 wT[3 * 64 * LDW];      // weights transposed: wT[j][n][k] = wj[k][n]
    __shared__ float sc[64], sh[64], bb[3][64];
    __shared__ float red[512];
    __shared__ float psum[128];
    int t = threadIdx.x;
    int bid = blockIdx.x;

    // --- per-block BN partial stats over rows bid*64..+63 ---
    {
        int c = t & 63, rg = t >> 6;
        int rb = bid * 64;
        float s = 0.f, s2 = 0.f;
        for(int r = rg; r < 64; r += 4){
            float v = x[(rb + r) * 64 + c];
            s += v; s2 += v * v;
        }
        red[t] = s; red[256 + t] = s2;
    }
    // zero the attn-merge counters for this iteration (128 of them, 256 blocks: bid<128 each zero one)
    if(t == 0 && bid < 128) mergecnt[bid] = 0u;
    __syncthreads();
    if(t < 128){
        int c2 = t & 63, h = t >> 6;
        float a = red[h * 256 + c2] + red[h * 256 + c2 + 64] + red[h * 256 + c2 + 128] + red[h * 256 + c2 + 192];
        atomicAdd(&sums[t], a);
    }
    if(t == 0){
        __threadfence();
        atomicAdd(ctr, 1u);
    }
    // --- weight staging (useful work while other blocks finish their stats) ---
    for(int i = t; i < 3 * 4096; i += 256){
        int j = i >> 12, e = i & 4095, k = e >> 6, n = e & 63;
        const float* wp = (j == 0) ? w1 : ((j == 1) ? w2 : w3);
        wT[j * 64 * LDW + n * LDW + k] = (f16)wp[e];
    }
    if(t < 64){ bb[0][t] = b1[t]; bb[1][t] = b2[t]; bb[2][t] = b3[t]; }
    // --- spin until all 256 blocks contributed ---
    if(t == 0){
        while(__hip_atomic_load(ctr, __ATOMIC_RELAXED, __HIP_MEMORY_SCOPE_AGENT) < 256u){
            __builtin_amdgcn_s_sleep(8);
        }
    }
    __syncthreads();
    if(t < 128)  // atomic loads: read at the coherence point (values were produced by atomics)
        psum[t] = __hip_atomic_load(&sums[t], __ATOMIC_RELAXED, __HIP_MEMORY_SCOPE_AGENT);
    __syncthreads();
    if(t < 64){
        float mean = psum[t] * (1.f / 16384.f);
        float var  = psum[64 + t] * (1.f / 16384.f) - mean * mean;
        float s = gamma[t] * rsqrtf(var + 1e-5f);
        sc[t] = s;
        sh[t] = beta[t] - mean * s;
    }
    __syncthreads();

    // --- BN apply + QKV (unchanged) ---
    int w = t >> 6, lane = t & 63, quad = lane >> 4, l15 = lane & 15;
    int rowb = bid * 64 + w * 16;
    int arow = rowb + l15;
    half8 a[2];
    #pragma unroll
    for(int kc = 0; kc < 2; kc++){
        f32x4 x0 = *(const f32x4*)&x[arow * 64 + kc * 32 + quad * 8];
        f32x4 x1 = *(const f32x4*)&x[arow * 64 + kc * 32 + quad * 8 + 4];
        half8 h;
        #pragma unroll
        for(int j = 0; j < 8; j++){
            int c = kc * 32 + quad * 8 + j;
            float xv = (j < 4) ? x0[j & 3] : x1[j & 3];
            h[j] = (f16)(xv * sc[c] + sh[c]);
        }
        a[kc] = h;
    }
    const f32x4 vzero = {0.f, 0.f, 0.f, 0.f};
    f32x4 acc[3][4];
    #pragma unroll
    for(int m = 0; m < 3; m++){
        #pragma unroll
        for(int nt = 0; nt < 4; nt++){
            acc[m][nt] = vzero;
            #pragma unroll
            for(int kc = 0; kc < 2; kc++){
                half8 bfr = *(half8*)&wT[m * 64 * LDW + (nt * 16 + l15) * LDW + kc * 32 + quad * 8];
                acc[m][nt] = __builtin_amdgcn_mfma_f32_16x16x32_f16(a[kc], bfr, acc[m][nt], 0, 0, 0);
            }
        }
    }
    const float qs = 0.18033688011112043f;  // log2(e)/8 : folds softmax scale + exp2 base change into Q
    #pragma unroll
    for(int nt = 0; nt < 4; nt++){
        #pragma unroll
        for(int r = 0; r < 4; r++){
            int row = rowb + quad * 4 + r;
            int col = nt * 16 + l15;
            Q[row * 64 + col]  = (f16)((acc[0][nt][r] + bb[0][col]) * qs);
            Kx[row * 64 + col] = (f16)(acc[1][nt][r] + bb[1][col]);
            Vt[((row >> 12) * 64 + col) * 4096 + (row & 4095)] = (f16)(acc[2][nt][r] + bb[2][col]);
        }
    }
}

// ---------------- K2: attention + split-K fixup merge (last block of each qg merges + W4 + residual) ----------------
// grid 1024: kq = bid&7 (K-eighth), qg = bid>>3 (128 x 128-row Q groups). 4 blocks/CU, 16 waves/CU.
// 32 Q-rows/wave; swapped-QK^T 32x32x16; in-register softmax (cvt_pkrtz + permlane32_swap).
// Partials NORMALIZED (o/l) f16 + l f32. The 8th finisher per qg merges its 128 rows in-kernel.
__global__ __launch_bounds__(256, 4) void k_attn(
    const f16* __restrict__ Q, const f16* __restrict__ Kx, const f16* __restrict__ Vt,
    f16* __restrict__ Oph, float* __restrict__ lw,
    const float* __restrict__ w4, const float* __restrict__ b4,
    const float* __restrict__ x, float* __restrict__ out,
    unsigned* __restrict__ mergecnt){
    __shared__ char smem[37892] __attribute__((aligned(16)));
    f16* KVs  = (f16*)smem;                   // [2][2*64*LDW] : 36864 B
    float* lred = (float*)(smem + 36864);     // [4][32] : 512 B
    int* isLastP = (int*)(smem + 37376);
    const int BUF = 2 * 64 * LDW;
    int t = threadIdx.x;
    int kq = blockIdx.x & 7, qg = blockIdx.x >> 3;   // qg in [0,128)
    int b = qg >> 5;
    int w = t >> 6, lane = t & 63, l31 = lane & 31, hi = lane >> 5;
    int qrow0 = qg * 128 + w * 32;

    // Q fragments (B-operand): lane holds qrow = qrow0+l31, d-elems dc*16 + hi*8 .. +7
    half8 aq[4];
    #pragma unroll
    for(int dc = 0; dc < 4; dc++)
        aq[dc] = *(const half8*)&Q[(qrow0 + l31) * 64 + dc * 16 + hi * 8];

    // staging: 1024 x 16B chunks per 64-col tile (512 K + 512 V^T); 4 chunks/thread
    const f16* gsrc[4];
    int loff[4], gstep[4];
    #pragma unroll
    for(int i = 0; i < 4; i++){
        int idx = t + i * 256;
        int rr = (idx >> 3) & 63, c8 = idx & 7, kt0 = kq * 8;
        if(idx < 512){
            loff[i] = rr * LDW + c8 * 8;
            gsrc[i] = &Kx[(b * 4096 + kt0 * 64 + rr) * 64 + c8 * 8];
            gstep[i] = 64 * 64;
        } else {
            loff[i] = 64 * LDW + rr * LDW + c8 * 8;
            gsrc[i] = &Vt[(b * 64 + rr) * 4096 + kt0 * 64 + c8 * 8];
            gstep[i] = 64;
        }
    }
    half8 pre[4];
    #pragma unroll
    for(int i = 0; i < 4; i++){ pre[i] = *(const half8*)gsrc[i]; gsrc[i] += gstep[i]; }
    #pragma unroll
    for(int i = 0; i < 4; i++) *(half8*)&KVs[loff[i]] = pre[i];

    f32x16 o[2];
    #pragma unroll
    for(int dt = 0; dt < 2; dt++)
        #pragma unroll
        for(int r = 0; r < 16; r++) o[dt][r] = 0.f;
    float lp = 0.f;

    __syncthreads();
    int cur = 0;
    for(int j = 0; j < 8; j++){
        if(j < 7){  // issue next-tile global loads early; consumed after compute (T14)
            #pragma unroll
            for(int i = 0; i < 4; i++){ pre[i] = *(const half8*)gsrc[i]; gsrc[i] += gstep[i]; }
        }
        const f16* Kb = KVs + cur * BUF;
        const f16* Vb = Kb + 64 * LDW;
        #pragma unroll
        for(int kt = 0; kt < 2; kt++){
            half8 ak[4];
            #pragma unroll
            for(int dc = 0; dc < 4; dc++)
                ak[dc] = *(const half8*)&Kb[(kt * 32 + l31) * LDW + dc * 16 + hi * 8];
            half8 vb[2][2];
            #pragma unroll
            for(int kc = 0; kc < 2; kc++)
                #pragma unroll
                for(int dt = 0; dt < 2; dt++)
                    vb[kc][dt] = *(const half8*)&Vb[(dt * 32 + l31) * LDW + kt * 32 + kc * 16 + hi * 8];
            f32x16 s;
            #pragma unroll
            for(int r = 0; r < 16; r++) s[r] = 0.f;
            #pragma unroll
            for(int dc = 0; dc < 4; dc++)
                s = __builtin_amdgcn_mfma_f32_32x32x16_f16(ak[dc], aq[dc], s, 0, 0, 0);
            // S^T: lane's 16 values belong to qrow = qrow0+l31; kcol_local = (r&3)+8*(r>>2)+4*hi
            float pf[16], ls = 0.f;
            #pragma unroll
            for(int r = 0; r < 16; r++){
                float p = __builtin_amdgcn_exp2f(fminf(s[r], 15.f));
                pf[r] = p; ls += p;
            }
            lp += ls;
            unsigned wv[4][2];
            #pragma unroll
            for(int g = 0; g < 4; g++){
                wv[g][0] = __builtin_bit_cast(unsigned, __builtin_amdgcn_cvt_pkrtz(pf[4*g+0], pf[4*g+1]));
                wv[g][1] = __builtin_bit_cast(unsigned, __builtin_amdgcn_cvt_pkrtz(pf[4*g+2], pf[4*g+3]));
            }
            #pragma unroll
            for(int kc = 0; kc < 2; kc++){
                unsigned x0 = wv[2*kc][0], y0 = wv[2*kc+1][0];
                unsigned x1 = wv[2*kc][1], y1 = wv[2*kc+1][1];
                asm("v_permlane32_swap_b32 %0, %1" : "+v"(x0), "+v"(y0));
                asm("v_permlane32_swap_b32 %0, %1" : "+v"(x1), "+v"(y1));
                u32x4 pw = {x0, x1, y0, y1};
                half8 pa = __builtin_bit_cast(half8, pw);
                #pragma unroll
                for(int dt = 0; dt < 2; dt++)
                    o[dt] = __builtin_amdgcn_mfma_f32_32x32x16_f16(pa, vb[kc][dt], o[dt], 0, 0, 0);
            }
        }
        if(j < 7){
            f16* wb = KVs + (cur ^ 1) * BUF;
            #pragma unroll
            for(int i = 0; i < 4; i++) *(half8*)(wb + loff[i]) = pre[i];
        }
        cur ^= 1;
        __syncthreads();
    }
    // row sums: lanes l and l+32 hold the same qrow
    {
        float v = lp + __shfl_xor(lp, 32);
        if(hi == 0){
            int row = qrow0 + l31;
            lw[kq * 16384 + row] = v;
            lred[w * 32 + l31] = __builtin_amdgcn_rcpf(v);
        }
    }
    // O layout: lane holds d = dt*32+l31; qrow = (r&3)+8*(r>>2)+4*hi
    #pragma unroll
    for(int r = 0; r < 16; r++){
        int qrl = (r & 3) + 8 * (r >> 2) + 4 * hi;
        float inv = lred[w * 32 + qrl];
        int row = qrow0 + qrl;
        #pragma unroll
        for(int dt = 0; dt < 2; dt++)
            Oph[kq * 1048576 + row * 64 + dt * 32 + l31] = (f16)(o[dt][r] * inv);
    }

    // ---------------- split-K fixup: last finisher of this qg merges 128 rows ----------------
    __threadfence();                 // each thread: own Oph/lw stores device-visible
    __syncthreads();
    if(t == 0){
        unsigned old = atomicAdd(&mergecnt[qg], 1u);
        *isLastP = (old == 7u);
    }
    __syncthreads();
    if(!*isLastP) return;
    __threadfence();                 // acquire: discard stale cached lines before reading peers' partials

    f16* Om   = (f16*)smem;          // 128*LDW f16 : 18432 B (LDS reuse; all threads past barrier)
    f16* wT4  = (f16*)(smem + 18432);// 64*LDW f16  : 9216 B
    float* b4f = (float*)(smem + 27648);
    int rb = qg * 128;
    for(int i = t; i < 4096; i += 256){
        int k = i >> 6, n = i & 63;
        wT4[n * LDW + k] = (f16)w4[i];
    }
    if(t < 64) b4f[t] = b4[t];
    for(int i = t; i < 1024; i += 256){
        int row = i >> 3, c8 = i & 7;
        int gr = rb + row;
        float num[8] = {0.f,0.f,0.f,0.f,0.f,0.f,0.f,0.f};
        float den = 0.f;
        #pragma unroll
        for(int s = 0; s < 8; s++){
            float li = lw[s * 16384 + gr];
            half8 ov = *(const half8*)&Oph[s * 1048576 + gr * 64 + c8 * 8];
            #pragma unroll
            for(int j = 0; j < 8; j++) num[j] += li * (float)ov[j];
            den += li;
        }
        float invd = 1.f / den;
        #pragma unroll
        for(int j = 0; j < 8; j++) Om[row * LDW + c8 * 8 + j] = (f16)(num[j] * invd);
    }
    __syncthreads();
    int quad = lane >> 4, l15 = lane & 15;
    #pragma unroll
    for(int rt = 0; rt < 2; rt++){
        int rloc = w * 32 + rt * 16;
        half8 a[2];
        #pragma unroll
        for(int kc = 0; kc < 2; kc++)
            a[kc] = *(half8*)&Om[(rloc + l15) * LDW + kc * 32 + quad * 8];
        #pragma unroll
        for(int nt = 0; nt < 4; nt++){
            f32x4 y = {0.f, 0.f, 0.f, 0.f};
            #pragma unroll
            for(int kc = 0; kc < 2; kc++){
                half8 bfr = *(half8*)&wT4[(nt * 16 + l15) * LDW + kc * 32 + quad * 8];
                y = __builtin_amdgcn_mfma_f32_16x16x32_f16(a[kc], bfr, y, 0, 0, 0);
            }
            #pragma unroll
            for(int r = 0; r < 4; r++){
                int row = rb + rloc + quad * 4 + r;
                int col = nt * 16 + l15;
                out[row * 64 + col] = y[r] + b4f[col] + x[row * 64 + col];
            }
        }
    }
}

extern "C" void kernel_launch(void* const* d_in, const int* in_sizes, int n_in,
                              void* d_out, int out_size, void* d_ws, size_t ws_size,
                              hipStream_t stream){
    (void)in_sizes; (void)n_in; (void)out_size; (void)ws_size;
    const float* x  = (const float*)d_in[0];
    const float* w1 = (const float*)d_in[1];
    const float* w2 = (const float*)d_in[2];
    const float* w3 = (const float*)d_in[3];
    const float* w4 = (const float*)d_in[4];
    const float* b1 = (const float*)d_in[5];
    const float* b2 = (const float*)d_in[6];
    const float* b3 = (const float*)d_in[7];
    const float* b4 = (const float*)d_in[8];
    const float* gm = (const float*)d_in[9];
    const float* bt = (const float*)d_in[10];
    char* ws = (char*)d_ws;
    f16* Q    = (f16*)(ws);
    f16* Kx   = (f16*)(ws + (size_t)(2u << 20));
    f16* Vt   = (f16*)(ws + (size_t)(4u << 20));
    float* sums = (float*)(ws + (size_t)(6u << 20));              // 128 f32
    unsigned* ctr = (unsigned*)(ws + (size_t)(6u << 20) + 512);   // 1 u32
    unsigned* mergecnt = (unsigned*)(ws + (size_t)(6u << 20) + 1024); // 128 u32
    f16* Oph  = (f16*)(ws + (size_t)(8u << 20));                  // 8 x 2MB (f16, normalized)
    float* lwp = (float*)(ws + (size_t)(24u << 20));              // 8 x 64KB

    hipMemsetAsync(ws + (size_t)(6u << 20), 0, 2048, stream);     // sums + ctr + mergecnt
    hipLaunchKernelGGL(k_qkv,  dim3(256),  dim3(256), 0, stream,
                       x, w1, w2, w3, b1, b2, b3, gm, bt, sums, ctr, mergecnt, Q, Kx, Vt);
    hipLaunchKernelGGL(k_attn, dim3(1024), dim3(256), 0, stream,
                       Q, Kx, Vt, Oph, lwp, w4, b4, x, (float*)d_out, mergecnt);
}

// Round 6
// 133.365 us; speedup vs baseline: 2.3072x; 2.3072x over previous
//
#include <hip/hip_runtime.h>

typedef _Float16 f16;
typedef _Float16 half8 __attribute__((ext_vector_type(8)));
typedef float f32x4 __attribute__((ext_vector_type(4)));
typedef float f32x16 __attribute__((ext_vector_type(16)));
typedef unsigned u32x4 __attribute__((ext_vector_type(4)));

#define LDW 72  // padded LDS leading dim (f16): 144B row stride

// ---------------- K1: BN stats (atomic accumulate) + co-resident spin + BN apply + QKV ----------------
// grid 256 = 1 block/CU guaranteed co-resident -> spin is safe.
// Stats travel ONLY through device-scope atomics (L2 coherence point) -> no fences needed.
__global__ __launch_bounds__(256) void k_qkv(
    const float* __restrict__ x,
    const float* __restrict__ w1, const float* __restrict__ w2, const float* __restrict__ w3,
    const float* __restrict__ b1, const float* __restrict__ b2, const float* __restrict__ b3,
    const float* __restrict__ gamma, const float* __restrict__ beta,
    float* __restrict__ sums, unsigned* __restrict__ ctr,
    f16* __restrict__ Q, f16* __restrict__ Kx, f16* __restrict__ Vt){
    __shared__ f16 wT[3 * 64 * LDW];      // weights transposed: wT[j][n][k] = wj[k][n]
    __shared__ float sc[64], sh[64], bb[3][64];
    __shared__ float red[512];
    __shared__ float psum[128];
    int t = threadIdx.x;
    int bid = blockIdx.x;

    // --- per-block BN partial stats over rows bid*64..+63 ---
    {
        int c = t & 63, rg = t >> 6;
        int rb = bid * 64;
        float s = 0.f, s2 = 0.f;
        for(int r = rg; r < 64; r += 4){
            float v = x[(rb + r) * 64 + c];
            s += v; s2 += v * v;
        }
        red[t] = s; red[256 + t] = s2;
    }
    __syncthreads();
    if(t < 128){
        int c2 = t & 63, h = t >> 6;
        float a = red[h * 256 + c2] + red[h * 256 + c2 + 64] + red[h * 256 + c2 + 128] + red[h * 256 + c2 + 192];
        atomicAdd(&sums[t], a);
    }
    __syncthreads();   // barrier drains vmcnt: this block's atomics complete before the bump
    if(t == 0)
        __hip_atomic_fetch_add(ctr, 1u, __ATOMIC_RELEASE, __HIP_MEMORY_SCOPE_AGENT);

    // --- weight staging (useful work overlapping other blocks' stats) ---
    for(int i = t; i < 3 * 4096; i += 256){
        int j = i >> 12, e = i & 4095, k = e >> 6, n = e & 63;
        const float* wp = (j == 0) ? w1 : ((j == 1) ? w2 : w3);
        wT[j * 64 * LDW + n * LDW + k] = (f16)wp[e];
    }
    if(t < 64){ bb[0][t] = b1[t]; bb[1][t] = b2[t]; bb[2][t] = b3[t]; }

    // --- spin until all 256 blocks contributed ---
    if(t == 0){
        while(__hip_atomic_load(ctr, __ATOMIC_ACQUIRE, __HIP_MEMORY_SCOPE_AGENT) < 256u)
            __builtin_amdgcn_s_sleep(4);
    }
    __syncthreads();
    if(t < 128)  // atomic loads read at the L2 coherence point (values produced by atomics)
        psum[t] = __hip_atomic_load(&sums[t], __ATOMIC_RELAXED, __HIP_MEMORY_SCOPE_AGENT);
    __syncthreads();
    if(t < 64){
        float mean = psum[t] * (1.f / 16384.f);
        float var  = psum[64 + t] * (1.f / 16384.f) - mean * mean;
        float s = gamma[t] * rsqrtf(var + 1e-5f);
        sc[t] = s;
        sh[t] = beta[t] - mean * s;
    }
    __syncthreads();

    // --- BN apply + QKV (verified r4 body) ---
    int w = t >> 6, lane = t & 63, quad = lane >> 4, l15 = lane & 15;
    int rowb = bid * 64 + w * 16;
    int arow = rowb + l15;
    half8 a[2];
    #pragma unroll
    for(int kc = 0; kc < 2; kc++){
        f32x4 x0 = *(const f32x4*)&x[arow * 64 + kc * 32 + quad * 8];
        f32x4 x1 = *(const f32x4*)&x[arow * 64 + kc * 32 + quad * 8 + 4];
        half8 h;
        #pragma unroll
        for(int j = 0; j < 8; j++){
            int c = kc * 32 + quad * 8 + j;
            float xv = (j < 4) ? x0[j & 3] : x1[j & 3];
            h[j] = (f16)(xv * sc[c] + sh[c]);
        }
        a[kc] = h;
    }
    const f32x4 vzero = {0.f, 0.f, 0.f, 0.f};
    f32x4 acc[3][4];
    #pragma unroll
    for(int m = 0; m < 3; m++){
        #pragma unroll
        for(int nt = 0; nt < 4; nt++){
            acc[m][nt] = vzero;
            #pragma unroll
            for(int kc = 0; kc < 2; kc++){
                half8 bfr = *(half8*)&wT[m * 64 * LDW + (nt * 16 + l15) * LDW + kc * 32 + quad * 8];
                acc[m][nt] = __builtin_amdgcn_mfma_f32_16x16x32_f16(a[kc], bfr, acc[m][nt], 0, 0, 0);
            }
        }
    }
    const float qs = 0.18033688011112043f;  // log2(e)/8 : folds softmax scale + exp2 base change into Q
    #pragma unroll
    for(int nt = 0; nt < 4; nt++){
        #pragma unroll
        for(int r = 0; r < 4; r++){
            int row = rowb + quad * 4 + r;
            int col = nt * 16 + l15;
            Q[row * 64 + col]  = (f16)((acc[0][nt][r] + bb[0][col]) * qs);
            Kx[row * 64 + col] = (f16)(acc[1][nt][r] + bb[1][col]);
            Vt[((row >> 12) * 64 + col) * 4096 + (row & 4095)] = (f16)(acc[2][nt][r] + bb[2][col]);
        }
    }
}

// ---------------- K2: streaming attention (verified r4 body + s_setprio around MFMA clusters) ----------------
// grid 1024: kq = bid&7 (K-eighth), qg = bid>>3 (128 x 128-row Q groups). 4 blocks/CU, 16 waves/CU.
// 32 Q-rows/wave; swapped-QK^T 32x32x16; in-register softmax (cvt_pkrtz + permlane32_swap).
// Partials stored NORMALIZED (o/l) as f16 + l as fp32; merged as weighted average in K3.
__global__ __launch_bounds__(256, 4) void k_attn(
    const f16* __restrict__ Q, const f16* __restrict__ Kx, const f16* __restrict__ Vt,
    f16* __restrict__ Oph, float* __restrict__ lw){
    __shared__ f16 KV[2][2 * 64 * LDW];
    __shared__ float lred[4][32];
    int t = threadIdx.x;
    int kq = blockIdx.x & 7, qg = blockIdx.x >> 3;   // qg in [0,128)
    int b = qg >> 5;
    int w = t >> 6, lane = t & 63, l31 = lane & 31, hi = lane >> 5;
    int qrow0 = qg * 128 + w * 32;
    const int BUF = 2 * 64 * LDW;

    // Q fragments (B-operand): lane holds qrow = qrow0+l31, d-elems dc*16 + hi*8 .. +7
    half8 aq[4];
    #pragma unroll
    for(int dc = 0; dc < 4; dc++)
        aq[dc] = *(const half8*)&Q[(qrow0 + l31) * 64 + dc * 16 + hi * 8];

    // staging: 1024 x 16B chunks per 64-col tile (512 K + 512 V^T); 4 chunks/thread
    const f16* gsrc[4];
    int loff[4], gstep[4];
    #pragma unroll
    for(int i = 0; i < 4; i++){
        int idx = t + i * 256;
        int rr = (idx >> 3) & 63, c8 = idx & 7, kt0 = kq * 8;
        if(idx < 512){
            loff[i] = rr * LDW + c8 * 8;
            gsrc[i] = &Kx[(b * 4096 + kt0 * 64 + rr) * 64 + c8 * 8];
            gstep[i] = 64 * 64;
        } else {
            loff[i] = 64 * LDW + rr * LDW + c8 * 8;
            gsrc[i] = &Vt[(b * 64 + rr) * 4096 + kt0 * 64 + c8 * 8];
            gstep[i] = 64;
        }
    }
    half8 pre[4];
    #pragma unroll
    for(int i = 0; i < 4; i++){ pre[i] = *(const half8*)gsrc[i]; gsrc[i] += gstep[i]; }
    #pragma unroll
    for(int i = 0; i < 4; i++) *(half8*)&KV[0][loff[i]] = pre[i];

    f32x16 o[2];
    #pragma unroll
    for(int dt = 0; dt < 2; dt++)
        #pragma unroll
        for(int r = 0; r < 16; r++) o[dt][r] = 0.f;
    float lp = 0.f;

    __syncthreads();
    int cur = 0;
    for(int j = 0; j < 8; j++){
        if(j < 7){  // issue next-tile global loads early; consumed after compute (T14)
            #pragma unroll
            for(int i = 0; i < 4; i++){ pre[i] = *(const half8*)gsrc[i]; gsrc[i] += gstep[i]; }
        }
        const f16* Kb = &KV[0][0] + cur * BUF;
        const f16* Vb = Kb + 64 * LDW;
        #pragma unroll
        for(int kt = 0; kt < 2; kt++){
            // K fragments (A-operand): lane holds kcol = kt*32+l31, d-elems dc*16 + hi*8
            half8 ak[4];
            #pragma unroll
            for(int dc = 0; dc < 4; dc++)
                ak[dc] = *(const half8*)&Kb[(kt * 32 + l31) * LDW + dc * 16 + hi * 8];
            // V fragments (B-operand): lane holds d = dt*32+l31, kcols kt*32 + kc*16 + hi*8
            half8 vb[2][2];
            #pragma unroll
            for(int kc = 0; kc < 2; kc++)
                #pragma unroll
                for(int dt = 0; dt < 2; dt++)
                    vb[kc][dt] = *(const half8*)&Vb[(dt * 32 + l31) * LDW + kt * 32 + kc * 16 + hi * 8];
            __builtin_amdgcn_s_setprio(1);
            f32x16 s;
            #pragma unroll
            for(int r = 0; r < 16; r++) s[r] = 0.f;
            #pragma unroll
            for(int dc = 0; dc < 4; dc++)
                s = __builtin_amdgcn_mfma_f32_32x32x16_f16(ak[dc], aq[dc], s, 0, 0, 0);
            __builtin_amdgcn_s_setprio(0);
            // S^T layout: lane's 16 values all belong to qrow = qrow0+l31; kcol_local = (r&3)+8*(r>>2)+4*hi
            float pf[16], ls = 0.f;
            #pragma unroll
            for(int r = 0; r < 16; r++){
                float p = __builtin_amdgcn_exp2f(fminf(s[r], 15.f));
                pf[r] = p; ls += p;
            }
            lp += ls;
            unsigned wv[4][2];
            #pragma unroll
            for(int g = 0; g < 4; g++){
                wv[g][0] = __builtin_bit_cast(unsigned, __builtin_amdgcn_cvt_pkrtz(pf[4*g+0], pf[4*g+1]));
                wv[g][1] = __builtin_bit_cast(unsigned, __builtin_amdgcn_cvt_pkrtz(pf[4*g+2], pf[4*g+3]));
            }
            // A-frag chunk kc (16 kcols): lane hi needs kcols kc*16+hi*8..+7
            __builtin_amdgcn_s_setprio(1);
            #pragma unroll
            for(int kc = 0; kc < 2; kc++){
                unsigned x0 = wv[2*kc][0], y0 = wv[2*kc+1][0];
                unsigned x1 = wv[2*kc][1], y1 = wv[2*kc+1][1];
                asm("v_permlane32_swap_b32 %0, %1" : "+v"(x0), "+v"(y0));
                asm("v_permlane32_swap_b32 %0, %1" : "+v"(x1), "+v"(y1));
                u32x4 pw = {x0, x1, y0, y1};
                half8 pa = __builtin_bit_cast(half8, pw);
                #pragma unroll
                for(int dt = 0; dt < 2; dt++)
                    o[dt] = __builtin_amdgcn_mfma_f32_32x32x16_f16(pa, vb[kc][dt], o[dt], 0, 0, 0);
            }
            __builtin_amdgcn_s_setprio(0);
        }
        if(j < 7){
            f16* wb = &KV[0][0] + (cur ^ 1) * BUF;
            #pragma unroll
            for(int i = 0; i < 4; i++) *(half8*)(wb + loff[i]) = pre[i];
        }
        cur ^= 1;
        __syncthreads();
    }
    // row sums: lanes l and l+32 hold the same qrow
    {
        float v = lp + __shfl_xor(lp, 32);
        if(hi == 0){
            int row = qrow0 + l31;
            lw[kq * 16384 + row] = v;
            lred[w][l31] = __builtin_amdgcn_rcpf(v);
        }
    }
    // O layout: lane holds d = dt*32+l31; qrow = (r&3)+8*(r>>2)+4*hi
    #pragma unroll
    for(int r = 0; r < 16; r++){
        int qrl = (r & 3) + 8 * (r >> 2) + 4 * hi;
        float inv = lred[w][qrl];
        int row = qrow0 + qrl;
        #pragma unroll
        for(int dt = 0; dt < 2; dt++)
            Oph[kq * 1048576 + row * 64 + dt * 32 + l31] = (f16)(o[dt][r] * inv);
    }
}

// ---------------- K3: weighted merge of normalized partials, W4 projection + bias + residual ----------------
__global__ __launch_bounds__(256) void k_merge(
    const f16* __restrict__ Oph, const float* __restrict__ lw,
    const float* __restrict__ w4, const float* __restrict__ b4,
    const float* __restrict__ x, float* __restrict__ out){
    __shared__ f16 Om[64 * LDW];
    __shared__ f16 wT[64 * LDW];
    __shared__ float b4f[64];
    int t = threadIdx.x;
    int rb = blockIdx.x * 64;
    for(int i = t; i < 4096; i += 256){
        int k = i >> 6, n = i & 63;
        wT[n * LDW + k] = (f16)w4[i];
    }
    if(t < 64) b4f[t] = b4[t];
    for(int i = t; i < 512; i += 256){
        int row = i >> 3, c8 = i & 7;
        int gr = rb + row;
        float num[8] = {0.f,0.f,0.f,0.f,0.f,0.f,0.f,0.f};
        float den = 0.f;
        #pragma unroll
        for(int s = 0; s < 8; s++){
            float li = lw[s * 16384 + gr];
            half8 ov = *(const half8*)&Oph[s * 1048576 + gr * 64 + c8 * 8];
            #pragma unroll
            for(int j = 0; j < 8; j++) num[j] += li * (float)ov[j];
            den += li;
        }
        float invd = 1.f / den;
        #pragma unroll
        for(int j = 0; j < 8; j++) Om[row * LDW + c8 * 8 + j] = (f16)(num[j] * invd);
    }
    __syncthreads();
    int w = t >> 6, lane = t & 63, quad = lane >> 4, l15 = lane & 15;
    half8 a[2];
    #pragma unroll
    for(int kc = 0; kc < 2; kc++)
        a[kc] = *(half8*)&Om[(w * 16 + l15) * LDW + kc * 32 + quad * 8];
    #pragma unroll
    for(int nt = 0; nt < 4; nt++){
        f32x4 y = {0.f, 0.f, 0.f, 0.f};
        #pragma unroll
        for(int kc = 0; kc < 2; kc++){
            half8 bfr = *(half8*)&wT[(nt * 16 + l15) * LDW + kc * 32 + quad * 8];
            y = __builtin_amdgcn_mfma_f32_16x16x32_f16(a[kc], bfr, y, 0, 0, 0);
        }
        #pragma unroll
        for(int r = 0; r < 4; r++){
            int row = rb + w * 16 + quad * 4 + r;
            int col = nt * 16 + l15;
            out[row * 64 + col] = y[r] + b4f[col] + x[row * 64 + col];
        }
    }
}

extern "C" void kernel_launch(void* const* d_in, const int* in_sizes, int n_in,
                              void* d_out, int out_size, void* d_ws, size_t ws_size,
                              hipStream_t stream){
    (void)in_sizes; (void)n_in; (void)out_size; (void)ws_size;
    const float* x  = (const float*)d_in[0];
    const float* w1 = (const float*)d_in[1];
    const float* w2 = (const float*)d_in[2];
    const float* w3 = (const float*)d_in[3];
    const float* w4 = (const float*)d_in[4];
    const float* b1 = (const float*)d_in[5];
    const float* b2 = (const float*)d_in[6];
    const float* b3 = (const float*)d_in[7];
    const float* b4 = (const float*)d_in[8];
    const float* gm = (const float*)d_in[9];
    const float* bt = (const float*)d_in[10];
    char* ws = (char*)d_ws;
    f16* Q    = (f16*)(ws);
    f16* Kx   = (f16*)(ws + (size_t)(2u << 20));
    f16* Vt   = (f16*)(ws + (size_t)(4u << 20));
    float* sums = (float*)(ws + (size_t)(6u << 20));              // 128 f32
    unsigned* ctr = (unsigned*)(ws + (size_t)(6u << 20) + 512);   // 1 u32
    f16* Oph  = (f16*)(ws + (size_t)(8u << 20));                  // 8 x 2MB (f16, normalized)
    float* lwp = (float*)(ws + (size_t)(24u << 20));              // 8 x 64KB

    hipMemsetAsync(ws + (size_t)(6u << 20), 0, 1024, stream);     // sums + ctr
    hipLaunchKernelGGL(k_qkv,  dim3(256),  dim3(256), 0, stream,
                       x, w1, w2, w3, b1, b2, b3, gm, bt, sums, ctr, Q, Kx, Vt);
    hipLaunchKernelGGL(k_attn, dim3(1024), dim3(256), 0, stream, Q, Kx, Vt, Oph, lwp);
    hipLaunchKernelGGL(k_merge, dim3(256), dim3(256), 0, stream, Oph, lwp, w4, b4, x, (float*)d_out);
}